// Round 1
// baseline (825.567 us; speedup 1.0000x reference)
//
#include <hip/hip_runtime.h>

// Problem constants (fixed by the reference file)
#define NN 50000
#define EE 800000
#define HH 128
#define LL 4
#define GG 64
#define NR 50048   // NN rounded up to 64 (mlp tile granularity)
#define NBN 12500  // ceil(NN/4) node-blocks per column-pass in agg

typedef short bf16x8 __attribute__((ext_vector_type(8)));
typedef float f32x4 __attribute__((ext_vector_type(4)));

// ---------------------------------------------------------------------------
// bf16 pack helpers (RTNE)
// ---------------------------------------------------------------------------
__device__ __forceinline__ unsigned bf_round(float f) {
  unsigned u = __float_as_uint(f);
  return (u + 0x7fffu + ((u >> 16) & 1u)) >> 16;
}
__device__ __forceinline__ unsigned bf_pack2(float lo, float hi) {
  return bf_round(lo) | (bf_round(hi) << 16);
}

// ---------------------------------------------------------------------------
// CSR build
// ---------------------------------------------------------------------------
__global__ __launch_bounds__(256) void count_kernel(const int* __restrict__ tgt,
                                                    int* __restrict__ cnt, int E) {
  int e = blockIdx.x * 256 + threadIdx.x;
  if (e < E) atomicAdd(&cnt[tgt[e]], 1);
}

__global__ __launch_bounds__(256) void blocksum_kernel(const int* __restrict__ cnt,
                                                       int* __restrict__ bs, int N) {
  int i = blockIdx.x * 256 + threadIdx.x;
  int v = (i < N) ? cnt[i] : 0;
  __shared__ int sm[256];
  sm[threadIdx.x] = v;
  __syncthreads();
  for (int s = 128; s >= 1; s >>= 1) {
    if (threadIdx.x < s) sm[threadIdx.x] += sm[threadIdx.x + s];
    __syncthreads();
  }
  if (threadIdx.x == 0) bs[blockIdx.x] = sm[0];
}

__global__ __launch_bounds__(256) void bs_scan_kernel(int* __restrict__ bs, int nb) {
  __shared__ int sm[256];
  int t = threadIdx.x;
  int v = (t < nb) ? bs[t] : 0;
  sm[t] = v;
  __syncthreads();
  for (int off = 1; off < 256; off <<= 1) {
    int u = (t >= off) ? sm[t - off] : 0;
    __syncthreads();
    sm[t] += u;
    __syncthreads();
  }
  if (t < nb) bs[t] = sm[t] - v;
  if (t == 255) bs[nb] = sm[255];
}

// also zeroes the scatter cursor (saves one memset dispatch)
__global__ __launch_bounds__(256) void blockscan_kernel(const int* __restrict__ cnt,
                                                        const int* __restrict__ bs,
                                                        int* __restrict__ rp,
                                                        int* __restrict__ cur, int N, int nb) {
  int b = blockIdx.x, t = threadIdx.x;
  int i = b * 256 + t;
  int v = (i < N) ? cnt[i] : 0;
  __shared__ int sm[256];
  sm[t] = v;
  __syncthreads();
  for (int off = 1; off < 256; off <<= 1) {
    int u = (t >= off) ? sm[t - off] : 0;
    __syncthreads();
    sm[t] += u;
    __syncthreads();
  }
  if (i < N) { rp[i] = sm[t] - v + bs[b]; cur[i] = 0; }
  if (b == 0 && t == 0) rp[N] = bs[nb];
}

__global__ __launch_bounds__(256) void scatter_kernel(const int* __restrict__ src,
                                                      const int* __restrict__ tgt,
                                                      const float* __restrict__ attr,
                                                      const int* __restrict__ rp,
                                                      int* __restrict__ cur,
                                                      int2* __restrict__ es, int E) {
  int e = blockIdx.x * 256 + threadIdx.x;
  if (e < E) {
    int t = tgt[e];
    int p = rp[t] + atomicAdd(&cur[t], 1);
    int2 rec;
    rec.x = src[e];
    rec.y = __float_as_int(attr[e]);
    es[p] = rec;
  }
}

// Fused one-time init: weight transpose+bf16 (2*L*128*128), vn init (G*H),
// part zero (G*H).
__global__ __launch_bounds__(256) void init_kernel(const float* __restrict__ W1,
                                                   const float* __restrict__ W2,
                                                   const float* __restrict__ emb,
                                                   short* __restrict__ wt1,
                                                   short* __restrict__ wt2,
                                                   float* __restrict__ vn,
                                                   float* __restrict__ part) {
  int idx = blockIdx.x * 256 + threadIdx.x;
  const int NW = 2 * LL * HH * HH;  // 131072
  if (idx < NW) {
    int m = idx >> 14;
    int r = idx & 16383;
    int n = r >> 7, k = r & 127;
    const float* W = (m < LL) ? (W1 + (size_t)m * 16384) : (W2 + (size_t)(m - LL) * 16384);
    short* D = (m < LL) ? (wt1 + (size_t)m * 16384) : (wt2 + (size_t)(m - LL) * 16384);
    D[n * 128 + k] = (short)bf_round(W[k * 128 + n]);
  } else if (idx < NW + GG * HH) {
    int i = idx - NW;
    vn[i] = emb[i & (HH - 1)];
  } else if (idx < NW + 2 * GG * HH) {
    part[idx - NW - GG * HH] = 0.f;
  }
}

// hbf[n] = bf16(h_prev[n] + vn[batch[n]] + edge_b), packed 2 cols per uint
// (row = 256 B). Folding edge_b here removes one VALU op per (edge,col) from
// agg's inner loop; the z-epilogue reads hp/vn directly so eb stays out of
// the (1+eps)(h+vn) term.
__global__ __launch_bounds__(256) void pack_kernel(const float4* __restrict__ hp, int pitch4,
                                                   const float4* __restrict__ vn,
                                                   const float4* __restrict__ ebias,
                                                   const int* __restrict__ batch,
                                                   uint2* __restrict__ hbf, int N) {
  int idx = blockIdx.x * 256 + threadIdx.x;
  if (idx >= N * (HH / 4)) return;
  int n = idx >> 5;  // HH/4 == 32
  int c4 = idx & 31;
  int g = batch[n];
  float4 a = hp[(size_t)n * pitch4 + c4];
  float4 b = vn[g * 32 + c4];
  float4 e = ebias[c4];
  uint2 o;
  o.x = bf_pack2(a.x + b.x + e.x, a.y + b.y + e.y);
  o.y = bf_pack2(a.z + b.z + e.z, a.w + b.w + e.w);
  hbf[idx] = o;
}

__device__ __forceinline__ void accum8s(float* acc, uint4 p, float a, float m,
                                        const float4& ew0, const float4& ew1) {
  acc[0] = fmaf(m, fmaxf(fmaf(a, ew0.x, __uint_as_float(p.x << 16)), 0.f), acc[0]);
  acc[1] = fmaf(m, fmaxf(fmaf(a, ew0.y, __uint_as_float(p.x & 0xffff0000u)), 0.f), acc[1]);
  acc[2] = fmaf(m, fmaxf(fmaf(a, ew0.z, __uint_as_float(p.y << 16)), 0.f), acc[2]);
  acc[3] = fmaf(m, fmaxf(fmaf(a, ew0.w, __uint_as_float(p.y & 0xffff0000u)), 0.f), acc[3]);
  acc[4] = fmaf(m, fmaxf(fmaf(a, ew1.x, __uint_as_float(p.z << 16)), 0.f), acc[4]);
  acc[5] = fmaf(m, fmaxf(fmaf(a, ew1.y, __uint_as_float(p.z & 0xffff0000u)), 0.f), acc[5]);
  acc[6] = fmaf(m, fmaxf(fmaf(a, ew1.z, __uint_as_float(p.w << 16)), 0.f), acc[6]);
  acc[7] = fmaf(m, fmaxf(fmaf(a, ew1.w, __uint_as_float(p.w & 0xffff0000u)), 0.f), acc[7]);
}

// z[n] = (1+eps)*(h[n]+vn[g]) + (1/deg) * sum_e relu(hbf[src_e] + attr_e*eW)
// COLUMN-SPLIT version: 4 passes over the edge list, each covering 32 of the
// 128 columns. Per-pass gather working set = hbf/4 = 3.2 MB < 4 MB per-XCD
// L2, so the random src-row gather becomes L2-resident instead of spilling
// ~70% of 205 MB/layer to Infinity Cache. Pass-major blockIdx ordering makes
// the execution wavefront sweep pass 0..3 (temporal column-phase separation).
// Wave layout: one wave per (node, pass); lane = edge-slot e (0..15) x
// col-lane c (0..3); one gather instruction covers 16 edges x 64-B quarter
// rows = 1 KB / 16 cache lines. Tail edges clamp to re-1 (duplicate lines
// coalesce; masked with m=0). Cross-edge-slot combine: 4 shuffle-xor rounds.
__global__ __launch_bounds__(256) void agg_kernel(const uint4* __restrict__ hbf4,
                                                  const float* __restrict__ hp, int pitch,
                                                  const float* __restrict__ vnp,
                                                  const int* __restrict__ batch,
                                                  const int2* __restrict__ es,
                                                  const int* __restrict__ rp,
                                                  const float* __restrict__ eW,
                                                  const float* __restrict__ epsp,
                                                  uint4* __restrict__ zb4, int N) {
  int wave = threadIdx.x >> 6;
  int lane = threadIdx.x & 63;
  int pass = blockIdx.x / NBN;            // 0..3 (compile-time magic div)
  int nb = blockIdx.x - pass * NBN;
  int n = nb * 4 + wave;
  if (n >= N) return;
  int e = lane >> 2;    // edge slot 0..15
  int c = lane & 3;     // col-lane: cols [pass*32 + c*8, +8)
  int col0 = pass * 32 + c * 8;
  float4 ew0 = *(const float4*)(eW + col0);
  float4 ew1 = *(const float4*)(eW + col0 + 4);
  int rs = rp[n], re = rp[n + 1];
  int cnt = re - rs;
  float acc[8];
#pragma unroll
  for (int j = 0; j < 8; ++j) acc[j] = 0.f;
  for (int k = 0; k < cnt; k += 16) {
    int idx = rs + min(k + e, cnt - 1);
    int2 ed = es[idx];
    float m = (k + e < cnt) ? 1.f : 0.f;
    uint4 p = hbf4[(size_t)ed.x * 16 + pass * 4 + c];
    accum8s(acc, p, __int_as_float(ed.y), m, ew0, ew1);
  }
  // combine partials across the 16 edge slots (lane bits 2..5)
#pragma unroll
  for (int j = 0; j < 8; ++j) {
    acc[j] += __shfl_xor(acc[j], 4);
    acc[j] += __shfl_xor(acc[j], 8);
    acc[j] += __shfl_xor(acc[j], 16);
    acc[j] += __shfl_xor(acc[j], 32);
  }
  if (e == 0) {
    int g = batch[n];
    const float* hrow = hp + (size_t)n * pitch + col0;
    const float* vrow = vnp + g * HH + col0;
    float4 h0 = *(const float4*)(hrow);
    float4 h1 = *(const float4*)(hrow + 4);
    float4 v0 = *(const float4*)(vrow);
    float4 v1 = *(const float4*)(vrow + 4);
    float inv = 1.f / fmaxf((float)cnt, 1.f);
    float onep = 1.f + epsp[0];
    uint4 o;
    o.x = bf_pack2(fmaf(onep, h0.x + v0.x, acc[0] * inv),
                   fmaf(onep, h0.y + v0.y, acc[1] * inv));
    o.y = bf_pack2(fmaf(onep, h0.z + v0.z, acc[2] * inv),
                   fmaf(onep, h0.w + v0.w, acc[3] * inv));
    o.z = bf_pack2(fmaf(onep, h1.x + v1.x, acc[4] * inv),
                   fmaf(onep, h1.y + v1.y, acc[5] * inv));
    o.w = bf_pack2(fmaf(onep, h1.z + v1.z, acc[6] * inv),
                   fmaf(onep, h1.w + v1.w, acc[7] * inv));
    zb4[(size_t)n * 16 + pass * 4 + c] = o;
  }
}

// h_new = relu(z @ W1 + b1) @ W2 + b2 -> out[:, layer*128:+128], via bf16 MFMA.
// Block = 64 rows, 4 waves; wave w owns rows [w*16, w*16+16); no barriers.
// Epilogue additionally accumulates the per-graph column sums (jumping-knowledge
// virtual-node input) via shuffle-reduce + atomicAdd into part[] when do_gs.
__global__ __launch_bounds__(256) void mlp_kernel(const unsigned* __restrict__ zb,
                                                  const short* __restrict__ wt1,
                                                  const float* __restrict__ b1,
                                                  const short* __restrict__ wt2,
                                                  const float* __restrict__ b2,
                                                  float* __restrict__ out,
                                                  float* __restrict__ part,
                                                  int do_gs, int layer, int N) {
  __shared__ char smem[64 * 272];
  int tid = threadIdx.x;
  int w = tid >> 6, lane = tid & 63;
  int l15 = lane & 15, q = lane >> 4;
  int row0 = blockIdx.x * 64;
  int wrow = w * 16;

  const uint4* z4 = (const uint4*)zb;
#pragma unroll
  for (int it = 0; it < 4; ++it) {
    int f = lane + it * 64;
    int r = f >> 4, c16 = f & 15;
    uint4 v = z4[(size_t)(row0 + wrow + r) * 16 + c16];
    *(uint4*)(&smem[(wrow + r) * 272 + c16 * 16]) = v;
  }

  f32x4 zero = {0.f, 0.f, 0.f, 0.f};
  f32x4 acc[8];
#pragma unroll
  for (int j = 0; j < 8; ++j) acc[j] = zero;

#pragma unroll
  for (int s = 0; s < 4; ++s) {
    bf16x8 af = *(const bf16x8*)(&smem[(wrow + l15) * 272 + (s * 32 + q * 8) * 2]);
#pragma unroll
    for (int j = 0; j < 8; ++j) {
      bf16x8 bf = *(const bf16x8*)(wt1 + (size_t)(j * 16 + l15) * 128 + s * 32 + q * 8);
      acc[j] = __builtin_amdgcn_mfma_f32_16x16x32_bf16(af, bf, acc[j], 0, 0, 0);
    }
  }
#pragma unroll
  for (int j = 0; j < 8; ++j) {
    float bv = b1[j * 16 + l15];
#pragma unroll
    for (int r = 0; r < 4; ++r) {
      float v = fmaxf(acc[j][r] + bv, 0.f);
      *(short*)(&smem[(wrow + q * 4 + r) * 272 + (j * 16 + l15) * 2]) = (short)bf_round(v);
    }
    acc[j] = zero;
  }
#pragma unroll
  for (int s = 0; s < 4; ++s) {
    bf16x8 af = *(const bf16x8*)(&smem[(wrow + l15) * 272 + (s * 32 + q * 8) * 2]);
#pragma unroll
    for (int j = 0; j < 8; ++j) {
      bf16x8 bf = *(const bf16x8*)(wt2 + (size_t)(j * 16 + l15) * 128 + s * 32 + q * 8);
      acc[j] = __builtin_amdgcn_mfma_f32_16x16x32_bf16(af, bf, acc[j], 0, 0, 0);
    }
  }
  int g0 = (int)(((long long)row0 * GG) / NN);
#pragma unroll
  for (int j = 0; j < 8; ++j) {
    float bv = b2[j * 16 + l15];
    float s0 = 0.f, s1 = 0.f;
#pragma unroll
    for (int r = 0; r < 4; ++r) {
      int row = row0 + wrow + q * 4 + r;
      if (row < N) {
        float v = acc[j][r] + bv;
        out[(size_t)row * (LL * HH) + layer * HH + j * 16 + l15] = v;
        if (do_gs) {
          int rel = (int)(((long long)row * GG) / NN) - g0;
          if (rel == 0) s0 += v; else s1 += v;
        }
      }
    }
    if (do_gs) {
      s0 += __shfl_xor(s0, 16); s0 += __shfl_xor(s0, 32);
      s1 += __shfl_xor(s1, 16); s1 += __shfl_xor(s1, 32);
      if (q == 0) {
        atomicAdd(&part[g0 * HH + j * 16 + l15], s0);
        if (s1 != 0.f) atomicAdd(&part[(g0 + 1) * HH + j * 16 + l15], s1);
      }
    }
  }
}

// vn = relu(relu((part + vn) @ W1 + b1) @ W2 + b2); re-zeroes part for the
// next layer's atomics. One block per graph.
__global__ __launch_bounds__(128) void vn_fused_kernel(float* __restrict__ part,
                                                       const float* __restrict__ W1,
                                                       const float* __restrict__ b1,
                                                       const float* __restrict__ W2,
                                                       const float* __restrict__ b2,
                                                       float* __restrict__ vn, int G) {
  int g = blockIdx.x, j = threadIdx.x;
  __shared__ float vr[128];
  __shared__ float tr[128];
  vr[j] = vn[g * HH + j] + part[g * HH + j];
  part[g * HH + j] = 0.f;
  __syncthreads();
  float a = b1[j];
  for (int k = 0; k < 128; ++k) a = fmaf(vr[k], W1[k * HH + j], a);
  tr[j] = fmaxf(a, 0.f);
  __syncthreads();
  float o = b2[j];
  for (int k = 0; k < 128; ++k) o = fmaf(tr[k], W2[k * HH + j], o);
  vn[g * HH + j] = fmaxf(o, 0.f);
}

extern "C" void kernel_launch(void* const* d_in, const int* in_sizes, int n_in,
                              void* d_out, int out_size, void* d_ws, size_t ws_size,
                              hipStream_t stream) {
  const int N = NN, E = EE, H = HH, L = LL, G = GG;
  const float* x          = (const float*)d_in[0];
  const float* edge_attr  = (const float*)d_in[1];
  const float* conv_W1    = (const float*)d_in[2];
  const float* conv_b1    = (const float*)d_in[3];
  const float* conv_W2    = (const float*)d_in[4];
  const float* conv_b2    = (const float*)d_in[5];
  const float* conv_eps   = (const float*)d_in[6];
  const float* edge_W     = (const float*)d_in[7];
  const float* edge_b     = (const float*)d_in[8];
  const float* vn_W1      = (const float*)d_in[9];
  const float* vn_b1      = (const float*)d_in[10];
  const float* vn_W2      = (const float*)d_in[11];
  const float* vn_b2      = (const float*)d_in[12];
  const float* vn_emb     = (const float*)d_in[13];
  const int*   edge_index = (const int*)d_in[14];
  const int*   batch      = (const int*)d_in[15];
  float* out = (float*)d_out;

  const int nb = (N + 255) / 256;

  // workspace carve-up
  char* ws = (char*)d_ws;
  size_t off = 0;
  auto take = [&](size_t bytes) -> void* {
    void* p = ws + off;
    off = (off + bytes + 255) & ~(size_t)255;
    return p;
  };
  int*      cnt  = (int*)take((size_t)N * 4);
  int*      cur  = (int*)take((size_t)N * 4);
  int*      rp   = (int*)take((size_t)(N + 1) * 4);
  int*      bs   = (int*)take((size_t)(nb + 1) * 4);
  int2*     es   = (int2*)take((size_t)E * 8);
  unsigned* hbf  = (unsigned*)take((size_t)N * (H / 2) * 4);   // bf16 h+vn+eb
  unsigned* zb   = (unsigned*)take((size_t)NR * (H / 2) * 4);  // bf16 z
  short*    wt1  = (short*)take((size_t)L * H * H * 2);        // bf16 W1^T
  short*    wt2  = (short*)take((size_t)L * H * H * 2);        // bf16 W2^T
  float*    part = (float*)take((size_t)G * H * 4);
  float*    vn   = (float*)take((size_t)G * H * 4);

  const int* src = edge_index;
  const int* tgt = edge_index + E;

  // CSR build
  hipMemsetAsync(cnt, 0, (size_t)N * 4, stream);
  count_kernel<<<(E + 255) / 256, 256, 0, stream>>>(tgt, cnt, E);
  blocksum_kernel<<<nb, 256, 0, stream>>>(cnt, bs, N);
  bs_scan_kernel<<<1, 256, 0, stream>>>(bs, nb);
  blockscan_kernel<<<nb, 256, 0, stream>>>(cnt, bs, rp, cur, N, nb);
  scatter_kernel<<<(E + 255) / 256, 256, 0, stream>>>(src, tgt, edge_attr, rp, cur, es, E);
  init_kernel<<<(2 * L * H * H + 2 * G * H + 255) / 256, 256, 0, stream>>>(
      conv_W1, conv_W2, vn_emb, wt1, wt2, vn, part);

  for (int i = 0; i < L; ++i) {
    const float* hp;
    int pitch;
    if (i == 0) { hp = x; pitch = H; }
    else        { hp = out + (size_t)(i - 1) * H; pitch = L * H; }
    pack_kernel<<<(N * (H / 4) + 255) / 256, 256, 0, stream>>>(
        (const float4*)hp, pitch / 4, (const float4*)vn,
        (const float4*)(edge_b + (size_t)i * H), batch, (uint2*)hbf, N);
    agg_kernel<<<4 * NBN, 256, 0, stream>>>(
        (const uint4*)hbf, hp, pitch, vn, batch, es, rp,
        edge_W + (size_t)i * H, conv_eps + i, (uint4*)zb, N);
    mlp_kernel<<<NR / 64, 256, 0, stream>>>(
        zb, wt1 + (size_t)i * H * H, conv_b1 + (size_t)i * H,
        wt2 + (size_t)i * H * H, conv_b2 + (size_t)i * H, out, part,
        (i < L - 1) ? 1 : 0, i, N);
    if (i < L - 1) {
      vn_fused_kernel<<<G, 128, 0, stream>>>(part, vn_W1 + (size_t)i * H * H,
                                             vn_b1 + (size_t)i * H,
                                             vn_W2 + (size_t)i * H * H,
                                             vn_b2 + (size_t)i * H, vn, G);
    }
  }
}

// Round 2
// 625.619 us; speedup vs baseline: 1.3196x; 1.3196x over previous
//
#include <hip/hip_runtime.h>

// Problem constants (fixed by the reference file)
#define NN 50000
#define EE 800000
#define HH 128
#define LL 4
#define GG 64
#define NR 50048   // NN rounded up to 64 (mlp tile granularity)

typedef short bf16x8 __attribute__((ext_vector_type(8)));
typedef float f32x4 __attribute__((ext_vector_type(4)));

// ---------------------------------------------------------------------------
// bf16 pack helpers (RTNE)
// ---------------------------------------------------------------------------
__device__ __forceinline__ unsigned bf_round(float f) {
  unsigned u = __float_as_uint(f);
  return (u + 0x7fffu + ((u >> 16) & 1u)) >> 16;
}
__device__ __forceinline__ unsigned bf_pack2(float lo, float hi) {
  return bf_round(lo) | (bf_round(hi) << 16);
}

// ---------------------------------------------------------------------------
// CSR build
// ---------------------------------------------------------------------------
__global__ __launch_bounds__(256) void count_kernel(const int* __restrict__ tgt,
                                                    int* __restrict__ cnt, int E) {
  int e = blockIdx.x * 256 + threadIdx.x;
  if (e < E) atomicAdd(&cnt[tgt[e]], 1);
}

__global__ __launch_bounds__(256) void blocksum_kernel(const int* __restrict__ cnt,
                                                       int* __restrict__ bs, int N) {
  int i = blockIdx.x * 256 + threadIdx.x;
  int v = (i < N) ? cnt[i] : 0;
  __shared__ int sm[256];
  sm[threadIdx.x] = v;
  __syncthreads();
  for (int s = 128; s >= 1; s >>= 1) {
    if (threadIdx.x < s) sm[threadIdx.x] += sm[threadIdx.x + s];
    __syncthreads();
  }
  if (threadIdx.x == 0) bs[blockIdx.x] = sm[0];
}

__global__ __launch_bounds__(256) void bs_scan_kernel(int* __restrict__ bs, int nb) {
  __shared__ int sm[256];
  int t = threadIdx.x;
  int v = (t < nb) ? bs[t] : 0;
  sm[t] = v;
  __syncthreads();
  for (int off = 1; off < 256; off <<= 1) {
    int u = (t >= off) ? sm[t - off] : 0;
    __syncthreads();
    sm[t] += u;
    __syncthreads();
  }
  if (t < nb) bs[t] = sm[t] - v;
  if (t == 255) bs[nb] = sm[255];
}

// also zeroes the scatter cursor (saves one memset dispatch)
__global__ __launch_bounds__(256) void blockscan_kernel(const int* __restrict__ cnt,
                                                        const int* __restrict__ bs,
                                                        int* __restrict__ rp,
                                                        int* __restrict__ cur, int N, int nb) {
  int b = blockIdx.x, t = threadIdx.x;
  int i = b * 256 + t;
  int v = (i < N) ? cnt[i] : 0;
  __shared__ int sm[256];
  sm[t] = v;
  __syncthreads();
  for (int off = 1; off < 256; off <<= 1) {
    int u = (t >= off) ? sm[t - off] : 0;
    __syncthreads();
    sm[t] += u;
    __syncthreads();
  }
  if (i < N) { rp[i] = sm[t] - v + bs[b]; cur[i] = 0; }
  if (b == 0 && t == 0) rp[N] = bs[nb];
}

__global__ __launch_bounds__(256) void scatter_kernel(const int* __restrict__ src,
                                                      const int* __restrict__ tgt,
                                                      const float* __restrict__ attr,
                                                      const int* __restrict__ rp,
                                                      int* __restrict__ cur,
                                                      int2* __restrict__ es, int E) {
  int e = blockIdx.x * 256 + threadIdx.x;
  if (e < E) {
    int t = tgt[e];
    int p = rp[t] + atomicAdd(&cur[t], 1);
    int2 rec;
    rec.x = src[e];
    rec.y = __float_as_int(attr[e]);
    es[p] = rec;
  }
}

// Fused one-time init: weight transpose+bf16 (2*L*128*128), vn init (G*H),
// part zero (G*H).
__global__ __launch_bounds__(256) void init_kernel(const float* __restrict__ W1,
                                                   const float* __restrict__ W2,
                                                   const float* __restrict__ emb,
                                                   short* __restrict__ wt1,
                                                   short* __restrict__ wt2,
                                                   float* __restrict__ vn,
                                                   float* __restrict__ part) {
  int idx = blockIdx.x * 256 + threadIdx.x;
  const int NW = 2 * LL * HH * HH;  // 131072
  if (idx < NW) {
    int m = idx >> 14;
    int r = idx & 16383;
    int n = r >> 7, k = r & 127;
    const float* W = (m < LL) ? (W1 + (size_t)m * 16384) : (W2 + (size_t)(m - LL) * 16384);
    short* D = (m < LL) ? (wt1 + (size_t)m * 16384) : (wt2 + (size_t)(m - LL) * 16384);
    D[n * 128 + k] = (short)bf_round(W[k * 128 + n]);
  } else if (idx < NW + GG * HH) {
    int i = idx - NW;
    vn[i] = emb[i & (HH - 1)];
  } else if (idx < NW + 2 * GG * HH) {
    part[idx - NW - GG * HH] = 0.f;
  }
}

// hbf[n] = bf16(h_prev[n] + vn[batch[n]] + edge_b), packed 2 cols per uint
// (row = 256 B). Folding edge_b here removes one VALU op per (edge,col) from
// agg's inner loop; the z-epilogue reads hp/vn directly so eb stays out of
// the (1+eps)(h+vn) term.
__global__ __launch_bounds__(256) void pack_kernel(const float4* __restrict__ hp, int pitch4,
                                                   const float4* __restrict__ vn,
                                                   const float4* __restrict__ ebias,
                                                   const int* __restrict__ batch,
                                                   uint2* __restrict__ hbf, int N) {
  int idx = blockIdx.x * 256 + threadIdx.x;
  if (idx >= N * (HH / 4)) return;
  int n = idx >> 5;  // HH/4 == 32
  int c4 = idx & 31;
  int g = batch[n];
  float4 a = hp[(size_t)n * pitch4 + c4];
  float4 b = vn[g * 32 + c4];
  float4 e = ebias[c4];
  uint2 o;
  o.x = bf_pack2(a.x + b.x + e.x, a.y + b.y + e.y);
  o.y = bf_pack2(a.z + b.z + e.z, a.w + b.w + e.w);
  hbf[idx] = o;
}

__device__ __forceinline__ void accum8s(float* acc, uint4 p, float a, float m,
                                        const float4& ew0, const float4& ew1) {
  acc[0] = fmaf(m, fmaxf(fmaf(a, ew0.x, __uint_as_float(p.x << 16)), 0.f), acc[0]);
  acc[1] = fmaf(m, fmaxf(fmaf(a, ew0.y, __uint_as_float(p.x & 0xffff0000u)), 0.f), acc[1]);
  acc[2] = fmaf(m, fmaxf(fmaf(a, ew0.z, __uint_as_float(p.y << 16)), 0.f), acc[2]);
  acc[3] = fmaf(m, fmaxf(fmaf(a, ew0.w, __uint_as_float(p.y & 0xffff0000u)), 0.f), acc[3]);
  acc[4] = fmaf(m, fmaxf(fmaf(a, ew1.x, __uint_as_float(p.z << 16)), 0.f), acc[4]);
  acc[5] = fmaf(m, fmaxf(fmaf(a, ew1.y, __uint_as_float(p.z & 0xffff0000u)), 0.f), acc[5]);
  acc[6] = fmaf(m, fmaxf(fmaf(a, ew1.z, __uint_as_float(p.w << 16)), 0.f), acc[6]);
  acc[7] = fmaf(m, fmaxf(fmaf(a, ew1.w, __uint_as_float(p.w & 0xffff0000u)), 0.f), acc[7]);
}

// z[n] = (1+eps)*(h[n]+vn[g]) + (1/deg) * sum_e relu(hbf[src_e] + attr_e*eW)
// Full-row gather (the Round-1 column split was falsified: per-XCD compulsory
// fills dominate FETCH and cannot be reduced by splitting; the split only
// added 4x issue overhead and exposed the gather latency chain).
// Wave per node; lane = (q=edge-slot 0..3, c=col16): one gather instruction
// covers 4 edges' full 256-B rows = 16 cache lines. 4-DEEP pipeline: each
// superiteration issues 4 independent es loads + 4 independent row gathers
// (64 lines in flight per wave, 2x round-0) so the average-degree-16 node
// completes with all misses overlapped. Tail edges clamp to cnt-1 (duplicate
// lines are L1 hits) and are masked with m=0. Cross-quad combine: 2
// shuffle-xor rounds.
__global__ __launch_bounds__(128) void agg_kernel(const uint4* __restrict__ hbf4,
                                                  const float* __restrict__ hp, int pitch,
                                                  const float* __restrict__ vnp,
                                                  const int* __restrict__ batch,
                                                  const int2* __restrict__ es,
                                                  const int* __restrict__ rp,
                                                  const float* __restrict__ eW,
                                                  const float* __restrict__ epsp,
                                                  uint4* __restrict__ zb4, int N) {
  int wave = threadIdx.x >> 6;
  int lane = threadIdx.x & 63;
  int n = blockIdx.x * 2 + wave;
  if (n >= N) return;
  int q = lane >> 4;   // edge sub-slot 0..3
  int c = lane & 15;   // cols [c*8, c*8+8)
  float4 ew0 = *(const float4*)(eW + c * 8);
  float4 ew1 = *(const float4*)(eW + c * 8 + 4);
  int rs = rp[n], re = rp[n + 1];
  int cnt = re - rs;
  float acc[8];
#pragma unroll
  for (int j = 0; j < 8; ++j) acc[j] = 0.f;
  for (int k = 0; k < cnt; k += 16) {
    int i0 = rs + min(k + q, cnt - 1);
    int i1 = rs + min(k + 4 + q, cnt - 1);
    int i2 = rs + min(k + 8 + q, cnt - 1);
    int i3 = rs + min(k + 12 + q, cnt - 1);
    int2 e0 = es[i0];
    int2 e1 = es[i1];
    int2 e2 = es[i2];
    int2 e3 = es[i3];
    uint4 p0 = hbf4[(size_t)e0.x * 16 + c];
    uint4 p1 = hbf4[(size_t)e1.x * 16 + c];
    uint4 p2 = hbf4[(size_t)e2.x * 16 + c];
    uint4 p3 = hbf4[(size_t)e3.x * 16 + c];
    float m0 = (k + q < cnt) ? 1.f : 0.f;
    float m1 = (k + 4 + q < cnt) ? 1.f : 0.f;
    float m2 = (k + 8 + q < cnt) ? 1.f : 0.f;
    float m3 = (k + 12 + q < cnt) ? 1.f : 0.f;
    accum8s(acc, p0, __int_as_float(e0.y), m0, ew0, ew1);
    accum8s(acc, p1, __int_as_float(e1.y), m1, ew0, ew1);
    accum8s(acc, p2, __int_as_float(e2.y), m2, ew0, ew1);
    accum8s(acc, p3, __int_as_float(e3.y), m3, ew0, ew1);
  }
  // cross-quad reduce: lanes with same c across quads hold partials
#pragma unroll
  for (int j = 0; j < 8; ++j) {
    acc[j] += __shfl_xor(acc[j], 16);
    acc[j] += __shfl_xor(acc[j], 32);
  }
  int g = batch[n];
  const float* hrow = hp + (size_t)n * pitch + c * 8;
  const float* vrow = vnp + g * HH + c * 8;
  float4 h0 = *(const float4*)(hrow);
  float4 h1 = *(const float4*)(hrow + 4);
  float4 v0 = *(const float4*)(vrow);
  float4 v1 = *(const float4*)(vrow + 4);
  float inv = 1.f / fmaxf((float)cnt, 1.f);
  float onep = 1.f + epsp[0];
  uint4 o;
  o.x = bf_pack2(fmaf(onep, h0.x + v0.x, acc[0] * inv),
                 fmaf(onep, h0.y + v0.y, acc[1] * inv));
  o.y = bf_pack2(fmaf(onep, h0.z + v0.z, acc[2] * inv),
                 fmaf(onep, h0.w + v0.w, acc[3] * inv));
  o.z = bf_pack2(fmaf(onep, h1.x + v1.x, acc[4] * inv),
                 fmaf(onep, h1.y + v1.y, acc[5] * inv));
  o.w = bf_pack2(fmaf(onep, h1.z + v1.z, acc[6] * inv),
                 fmaf(onep, h1.w + v1.w, acc[7] * inv));
  if (q == 0) zb4[(size_t)n * 16 + c] = o;
}

// h_new = relu(z @ W1 + b1) @ W2 + b2 -> out[:, layer*128:+128], via bf16 MFMA.
// Block = 64 rows, 4 waves; wave w owns rows [w*16, w*16+16); no barriers.
// Epilogue additionally accumulates the per-graph column sums (jumping-knowledge
// virtual-node input) via shuffle-reduce + atomicAdd into part[] when do_gs.
__global__ __launch_bounds__(256) void mlp_kernel(const unsigned* __restrict__ zb,
                                                  const short* __restrict__ wt1,
                                                  const float* __restrict__ b1,
                                                  const short* __restrict__ wt2,
                                                  const float* __restrict__ b2,
                                                  float* __restrict__ out,
                                                  float* __restrict__ part,
                                                  int do_gs, int layer, int N) {
  __shared__ char smem[64 * 272];
  int tid = threadIdx.x;
  int w = tid >> 6, lane = tid & 63;
  int l15 = lane & 15, q = lane >> 4;
  int row0 = blockIdx.x * 64;
  int wrow = w * 16;

  const uint4* z4 = (const uint4*)zb;
#pragma unroll
  for (int it = 0; it < 4; ++it) {
    int f = lane + it * 64;
    int r = f >> 4, c16 = f & 15;
    uint4 v = z4[(size_t)(row0 + wrow + r) * 16 + c16];
    *(uint4*)(&smem[(wrow + r) * 272 + c16 * 16]) = v;
  }

  f32x4 zero = {0.f, 0.f, 0.f, 0.f};
  f32x4 acc[8];
#pragma unroll
  for (int j = 0; j < 8; ++j) acc[j] = zero;

#pragma unroll
  for (int s = 0; s < 4; ++s) {
    bf16x8 af = *(const bf16x8*)(&smem[(wrow + l15) * 272 + (s * 32 + q * 8) * 2]);
#pragma unroll
    for (int j = 0; j < 8; ++j) {
      bf16x8 bf = *(const bf16x8*)(wt1 + (size_t)(j * 16 + l15) * 128 + s * 32 + q * 8);
      acc[j] = __builtin_amdgcn_mfma_f32_16x16x32_bf16(af, bf, acc[j], 0, 0, 0);
    }
  }
#pragma unroll
  for (int j = 0; j < 8; ++j) {
    float bv = b1[j * 16 + l15];
#pragma unroll
    for (int r = 0; r < 4; ++r) {
      float v = fmaxf(acc[j][r] + bv, 0.f);
      *(short*)(&smem[(wrow + q * 4 + r) * 272 + (j * 16 + l15) * 2]) = (short)bf_round(v);
    }
    acc[j] = zero;
  }
#pragma unroll
  for (int s = 0; s < 4; ++s) {
    bf16x8 af = *(const bf16x8*)(&smem[(wrow + l15) * 272 + (s * 32 + q * 8) * 2]);
#pragma unroll
    for (int j = 0; j < 8; ++j) {
      bf16x8 bf = *(const bf16x8*)(wt2 + (size_t)(j * 16 + l15) * 128 + s * 32 + q * 8);
      acc[j] = __builtin_amdgcn_mfma_f32_16x16x32_bf16(af, bf, acc[j], 0, 0, 0);
    }
  }
  int g0 = (int)(((long long)row0 * GG) / NN);
#pragma unroll
  for (int j = 0; j < 8; ++j) {
    float bv = b2[j * 16 + l15];
    float s0 = 0.f, s1 = 0.f;
#pragma unroll
    for (int r = 0; r < 4; ++r) {
      int row = row0 + wrow + q * 4 + r;
      if (row < N) {
        float v = acc[j][r] + bv;
        out[(size_t)row * (LL * HH) + layer * HH + j * 16 + l15] = v;
        if (do_gs) {
          int rel = (int)(((long long)row * GG) / NN) - g0;
          if (rel == 0) s0 += v; else s1 += v;
        }
      }
    }
    if (do_gs) {
      s0 += __shfl_xor(s0, 16); s0 += __shfl_xor(s0, 32);
      s1 += __shfl_xor(s1, 16); s1 += __shfl_xor(s1, 32);
      if (q == 0) {
        atomicAdd(&part[g0 * HH + j * 16 + l15], s0);
        if (s1 != 0.f) atomicAdd(&part[(g0 + 1) * HH + j * 16 + l15], s1);
      }
    }
  }
}

// vn = relu(relu((part + vn) @ W1 + b1) @ W2 + b2); re-zeroes part for the
// next layer's atomics. One block per graph.
__global__ __launch_bounds__(128) void vn_fused_kernel(float* __restrict__ part,
                                                       const float* __restrict__ W1,
                                                       const float* __restrict__ b1,
                                                       const float* __restrict__ W2,
                                                       const float* __restrict__ b2,
                                                       float* __restrict__ vn, int G) {
  int g = blockIdx.x, j = threadIdx.x;
  __shared__ float vr[128];
  __shared__ float tr[128];
  vr[j] = vn[g * HH + j] + part[g * HH + j];
  part[g * HH + j] = 0.f;
  __syncthreads();
  float a = b1[j];
  for (int k = 0; k < 128; ++k) a = fmaf(vr[k], W1[k * HH + j], a);
  tr[j] = fmaxf(a, 0.f);
  __syncthreads();
  float o = b2[j];
  for (int k = 0; k < 128; ++k) o = fmaf(tr[k], W2[k * HH + j], o);
  vn[g * HH + j] = fmaxf(o, 0.f);
}

extern "C" void kernel_launch(void* const* d_in, const int* in_sizes, int n_in,
                              void* d_out, int out_size, void* d_ws, size_t ws_size,
                              hipStream_t stream) {
  const int N = NN, E = EE, H = HH, L = LL, G = GG;
  const float* x          = (const float*)d_in[0];
  const float* edge_attr  = (const float*)d_in[1];
  const float* conv_W1    = (const float*)d_in[2];
  const float* conv_b1    = (const float*)d_in[3];
  const float* conv_W2    = (const float*)d_in[4];
  const float* conv_b2    = (const float*)d_in[5];
  const float* conv_eps   = (const float*)d_in[6];
  const float* edge_W     = (const float*)d_in[7];
  const float* edge_b     = (const float*)d_in[8];
  const float* vn_W1      = (const float*)d_in[9];
  const float* vn_b1      = (const float*)d_in[10];
  const float* vn_W2      = (const float*)d_in[11];
  const float* vn_b2      = (const float*)d_in[12];
  const float* vn_emb     = (const float*)d_in[13];
  const int*   edge_index = (const int*)d_in[14];
  const int*   batch      = (const int*)d_in[15];
  float* out = (float*)d_out;

  const int nb = (N + 255) / 256;

  // workspace carve-up
  char* ws = (char*)d_ws;
  size_t off = 0;
  auto take = [&](size_t bytes) -> void* {
    void* p = ws + off;
    off = (off + bytes + 255) & ~(size_t)255;
    return p;
  };
  int*      cnt  = (int*)take((size_t)N * 4);
  int*      cur  = (int*)take((size_t)N * 4);
  int*      rp   = (int*)take((size_t)(N + 1) * 4);
  int*      bs   = (int*)take((size_t)(nb + 1) * 4);
  int2*     es   = (int2*)take((size_t)E * 8);
  unsigned* hbf  = (unsigned*)take((size_t)N * (H / 2) * 4);   // bf16 h+vn+eb
  unsigned* zb   = (unsigned*)take((size_t)NR * (H / 2) * 4);  // bf16 z
  short*    wt1  = (short*)take((size_t)L * H * H * 2);        // bf16 W1^T
  short*    wt2  = (short*)take((size_t)L * H * H * 2);        // bf16 W2^T
  float*    part = (float*)take((size_t)G * H * 4);
  float*    vn   = (float*)take((size_t)G * H * 4);

  const int* src = edge_index;
  const int* tgt = edge_index + E;

  // CSR build
  hipMemsetAsync(cnt, 0, (size_t)N * 4, stream);
  count_kernel<<<(E + 255) / 256, 256, 0, stream>>>(tgt, cnt, E);
  blocksum_kernel<<<nb, 256, 0, stream>>>(cnt, bs, N);
  bs_scan_kernel<<<1, 256, 0, stream>>>(bs, nb);
  blockscan_kernel<<<nb, 256, 0, stream>>>(cnt, bs, rp, cur, N, nb);
  scatter_kernel<<<(E + 255) / 256, 256, 0, stream>>>(src, tgt, edge_attr, rp, cur, es, E);
  init_kernel<<<(2 * L * H * H + 2 * G * H + 255) / 256, 256, 0, stream>>>(
      conv_W1, conv_W2, vn_emb, wt1, wt2, vn, part);

  for (int i = 0; i < L; ++i) {
    const float* hp;
    int pitch;
    if (i == 0) { hp = x; pitch = H; }
    else        { hp = out + (size_t)(i - 1) * H; pitch = L * H; }
    pack_kernel<<<(N * (H / 4) + 255) / 256, 256, 0, stream>>>(
        (const float4*)hp, pitch / 4, (const float4*)vn,
        (const float4*)(edge_b + (size_t)i * H), batch, (uint2*)hbf, N);
    agg_kernel<<<(N + 1) / 2, 128, 0, stream>>>(
        (const uint4*)hbf, hp, pitch, vn, batch, es, rp,
        edge_W + (size_t)i * H, conv_eps + i, (uint4*)zb, N);
    mlp_kernel<<<NR / 64, 256, 0, stream>>>(
        zb, wt1 + (size_t)i * H * H, conv_b1 + (size_t)i * H,
        wt2 + (size_t)i * H * H, conv_b2 + (size_t)i * H, out, part,
        (i < L - 1) ? 1 : 0, i, N);
    if (i < L - 1) {
      vn_fused_kernel<<<G, 128, 0, stream>>>(part, vn_W1 + (size_t)i * H * H,
                                             vn_b1 + (size_t)i * H,
                                             vn_W2 + (size_t)i * H * H,
                                             vn_b2 + (size_t)i * H, vn, G);
    }
  }
}